// Round 5
// baseline (151.600 us; speedup 1.0000x reference)
//
#include <hip/hip_runtime.h>
#include <hip/hip_fp16.h>

typedef unsigned short u16;
typedef unsigned int   u32;
typedef __bf16 bf16x8 __attribute__((ext_vector_type(8)));
typedef float  f32x4  __attribute__((ext_vector_type(4)));

// ---------------- problem constants ----------------
constexpr int BB   = 16;            // batch
constexpr int S    = 4096;          // seq len
constexpr int M    = BB * S;        // 65536 rows
constexpr int DIN  = 64;
constexpr int H    = 512;
constexpr int DI   = 768;
constexpr int N2   = 1536;          // 2*DI
constexpr int CL   = 128;           // chunk length
constexpr int NCHUNK = M / CL;      // 512 chunks total
constexpr int NSEG  = NCHUNK * 4;   // 2048 segments (32 rows each)
constexpr int SEGB  = S / 32;       // 128 segments per batch
constexpr int DTILES = 12;          // 768 d / 64 d per tile

// ---------------- workspace layout (bytes) — total ~24.3 MB ----------------
constexpr size_t OFF_XB    = 0;                    // u16 [65536][64]  = 8388608
constexpr size_t OFF_B2C   = 8388608;              // u16 [1536][64]   = 196608
constexpr size_t OFF_WC    = 8585216;              // f32 [768] (pad 4096)
constexpr size_t OFF_SEGC  = 8589312;              // f32 [2048][768]  = 6291456
constexpr size_t OFF_SEGVH = 14880768;             // f32 [2048][768]  (V, then Hin in-place)
constexpr size_t OFF_PART  = 21172224;             // f32 [12][65536]  = 3145728

constexpr float L2E = 1.4426950408889634f;

__device__ __forceinline__ u16 f2bf(float f) {
  u32 u = __float_as_uint(f);
  u32 r = (u + 0x7FFFu + ((u >> 16) & 1u)) >> 16;
  return (u16)r;
}

// swizzled cvl slot (u32 [128][64]): kills 4-way conflict on activation stores
__device__ __forceinline__ int cvs(int row, int d) {
  return row * 64 + (d ^ (((row >> 2) & 3) << 4));
}

// ---------------- prep: x f32 -> bf16 ----------------
__global__ __launch_bounds__(256) void prep_xb(const float* __restrict__ x,
                                               u16* __restrict__ xb) {
  size_t i = (size_t)(blockIdx.x * 256 + threadIdx.x) * 8;   // 4194304 elems
  float4 f0 = *(const float4*)(x + i);
  float4 f1 = *(const float4*)(x + i + 4);
  u32 w0 = f2bf(f0.x) | ((u32)f2bf(f0.y) << 16);
  u32 w1 = f2bf(f0.z) | ((u32)f2bf(f0.w) << 16);
  u32 w2 = f2bf(f1.x) | ((u32)f2bf(f1.y) << 16);
  u32 w3 = f2bf(f1.z) | ((u32)f2bf(f1.w) << 16);
  uint4 o = make_uint4(w0, w1, w2, w3);
  *(uint4*)(xb + i) = o;
}

// ---------------- prep: B2c[n][k] = bf16( (W_in @ W_hg)[k][pi(n)] ) --------
// pi: n = 32g + r : r<16 -> hidden col (16g+r) ; r>=16 -> gate col (768+16g+(r-16))
__global__ __launch_bounds__(256) void prep_b2c(const float* __restrict__ Win,
                                                const float* __restrict__ Whg,
                                                u16* __restrict__ B2c) {
  __shared__ float Wl[64][65];
  const int tid = threadIdx.x;
  const int k = tid & 63;
  const int nloc = tid >> 6;                  // 0..3
  const int n = blockIdx.x * 4 + nloc;        // 384 blocks -> 1536 n
  const int g = n >> 5, r = n & 31;
  const int col = (r < 16) ? (g * 16 + r) : (DI + g * 16 + (r - 16));
  float acc = 0.f;
  for (int jc = 0; jc < H; jc += 64) {
    const int jl = tid & 63, k0 = tid >> 6;
    #pragma unroll
    for (int s = 0; s < 16; ++s) {
      int kr = k0 + 4 * s;
      Wl[kr][jl] = Win[kr * H + jc + jl];
    }
    __syncthreads();
    #pragma unroll 8
    for (int j = 0; j < 64; ++j)
      acc = fmaf(Wl[k][j], Whg[(size_t)(jc + j) * N2 + col], acc);
    __syncthreads();
  }
  B2c[n * 64 + k] = f2bf(acc);
}

// ---------------- prep: wcomb[d] = W_out[d,:] . W_final ----------------
__global__ __launch_bounds__(256) void prep_wcomb(const float* __restrict__ Wout,
                                                  const float* __restrict__ Wfin,
                                                  float* __restrict__ wc) {
  int wv = threadIdx.x >> 6, ln = threadIdx.x & 63;
  int d = blockIdx.x * 4 + wv;                // 192 blocks -> 768 d
  const float* row = Wout + (size_t)d * H;
  float s = 0.f;
  #pragma unroll
  for (int j = 0; j < 8; ++j) {
    int k = j * 64 + ln;
    s += row[k] * Wfin[k];
  }
  #pragma unroll
  for (int off = 32; off; off >>= 1) s += __shfl_xor(s, off);
  if (ln == 0) wc[d] = s;
}

// -------- fused: GEMM(K=64) + activation + segment scan --------
// PASS 1: per-SEGMENT (32-row) summaries -> SegC, SegV (global)
// PASS 2: read segment carry (SegVH==Hin), apply + fused wcomb dot -> part
template<int PASS>
__global__ __launch_bounds__(256) void fused_gemm_scan(
    const u16* __restrict__ xb, const u16* __restrict__ B2c,
    const float* __restrict__ Hin, const float* __restrict__ wcomb,
    float* __restrict__ SegC, float* __restrict__ SegV,
    float* __restrict__ part) {
  __shared__ __align__(16) u16 AB[16384];     // A [0..8191], B [8192..]; later cvl [128][64] u32
  u32* cvl = (u32*)AB;

  const int tid = threadIdx.x, wv = tid >> 6, ln = tid & 63;
  const int nt = blockIdx.x % DTILES, ck = blockIdx.x / DTILES;
  const int m0 = ck * CL;
  const int wr = wv >> 1, wcol = wv & 1;
  const int lrow = ln & 15, hi4 = ln >> 4;

  // stage A (128x64 bf16) and B (128x64 bf16); XOR-swizzled 16B slots
  {
    const uint4* gA = (const uint4*)(xb + (size_t)m0 * 64);
    const uint4* gB = (const uint4*)(B2c + (size_t)nt * 128 * 64);
    uint4* lA = (uint4*)AB;
    uint4* lB = (uint4*)(AB + 8192);
    #pragma unroll
    for (int j = 0; j < 4; ++j) {
      int q = j * 256 + tid;                  // slot id 0..1023 (8 slots/row)
      int qs = (q & ~7) | ((q & 7) ^ ((q >> 3) & 7));
      lA[qs] = gA[q];
      lB[qs] = gB[q];
    }
  }
  __syncthreads();

  f32x4 acc[4][4] = {};
  {
    const u16* Al = AB;
    const u16* Bl = AB + 8192;
    #pragma unroll
    for (int kk = 0; kk < 2; ++kk) {
      bf16x8 af[4], bfr[4];
      #pragma unroll
      for (int i = 0; i < 4; ++i) {
        int row = wr * 64 + i * 16 + lrow;
        af[i] = *(const bf16x8*)&Al[row * 64 + (((kk * 4 + hi4) ^ (row & 7)) << 3)];
      }
      #pragma unroll
      for (int j = 0; j < 4; ++j) {
        int row = wcol * 64 + j * 16 + lrow;
        bfr[j] = *(const bf16x8*)&Bl[row * 64 + (((kk * 4 + hi4) ^ (row & 7)) << 3)];
      }
      #pragma unroll
      for (int i = 0; i < 4; ++i)
        #pragma unroll
        for (int j = 0; j < 4; ++j)
          acc[i][j] = __builtin_amdgcn_mfma_f32_16x16x32_bf16(af[i], bfr[j], acc[i][j], 0, 0, 0);
    }
  }
  __syncthreads();   // LDS reads done -> safe to overwrite tile as cvl

  // activation; fragment pair (2jp, 2jp+1) = (hidden, gate) of the SAME d
  #pragma unroll
  for (int i = 0; i < 4; ++i)
    #pragma unroll
    for (int jp = 0; jp < 2; ++jp) {
      f32x4 hid = acc[i][2 * jp + 0];
      f32x4 gat = acc[i][2 * jp + 1];
      const int dl = (wcol * 2 + jp) * 16 + lrow;   // 0..63
      #pragma unroll
      for (int r = 0; r < 4; ++r) {
        int row = wr * 64 + i * 16 + hi4 * 4 + r;   // 0..127
        float gate = gat[r], hidden = hid[r];
        float eg  = __builtin_amdgcn_exp2f(gate * L2E);
        float cc  = __builtin_amdgcn_rcpf(1.0f + eg);     // sigmoid(-gate)
        float zz  = eg * cc;                              // sigmoid(gate)
        float gneg = __builtin_amdgcn_rcpf(
                        1.0f + __builtin_amdgcn_exp2f(-hidden * L2E));
        float gg  = (hidden >= 0.0f) ? (hidden + 0.5f) : gneg;
        float vv  = zz * gg;
        __half2 p = __floats2half2_rn(cc, vv);
        cvl[cvs(row, dl)] = *(const u32*)&p;
      }
    }
  __syncthreads();

  const int seg = ck * 4 + wv;                // global segment id
  if (PASS == 1) {
    // segment scan: 32 rows, d = lane -> global summaries
    float Cp = 1.f, Vp = 0.f;
    #pragma unroll 8
    for (int tt = 0; tt < 32; ++tt) {
      u32 u = cvl[cvs(wv * 32 + tt, ln)];
      __half2 hv = *(const __half2*)&u;
      float c = __half2float(__low2half(hv));
      float v = __half2float(__high2half(hv));
      Vp = fmaf(c, Vp, v);
      Cp *= c;
    }
    SegC[(size_t)seg * DI + nt * 64 + ln] = Cp;
    SegV[(size_t)seg * DI + nt * 64 + ln] = Vp;
  } else {
    // carried apply + in-place rotated pv store (wave owns its 32 rows)
    float h = Hin[(size_t)seg * DI + nt * 64 + ln];
    const float wd = wcomb[nt * 64 + ln];
    #pragma unroll 4
    for (int tt = 0; tt < 32; ++tt) {
      const int t = wv * 32 + tt;
      u32 u = cvl[cvs(t, ln)];
      __half2 hv = *(const __half2*)&u;
      float c = __half2float(__low2half(hv));
      float v = __half2float(__high2half(hv));
      h = fmaf(c, h, v);
      float pv = h * wd;
      cvl[t * 64 + ((ln + t) & 63)] = __float_as_uint(pv);
    }
    __syncthreads();
    // row reduction: 2 threads per row, rotated (conflict-free) reads
    const int row = tid >> 1, half = tid & 1;
    float s = 0.f;
    #pragma unroll 8
    for (int jj = 0; jj < 32; ++jj) {
      int idx = (half * 32 + jj + row) & 63;
      s += __uint_as_float(cvl[row * 64 + idx]);
    }
    s += __shfl_xor(s, 1);
    if (half == 0) part[(size_t)nt * M + m0 + row] = s;
  }
}

// ------- cross-segment carry scan; converts SegVH: V -> Hin in place -------
__global__ __launch_bounds__(768) void scan_carry(const float* __restrict__ SegC,
                                                  float* __restrict__ SegVH) {
  const int b = blockIdx.x, d = threadIdx.x;
  float carry = 0.f;
  for (int q = 0; q < SEGB; ++q) {
    size_t idx = (size_t)(b * SEGB + q) * DI + d;
    float tmp = fmaf(SegC[idx], carry, SegVH[idx]);
    SegVH[idx] = carry;
    carry = tmp;
  }
}

// ---------------- final: sum 12 d-tile partials ----------------
__global__ __launch_bounds__(256) void reduce12(const float* __restrict__ part,
                                                float* __restrict__ out) {
  int i = blockIdx.x * 256 + threadIdx.x;     // 65536
  float s = 0.f;
  #pragma unroll
  for (int w = 0; w < DTILES; ++w) s += part[(size_t)w * M + i];
  out[i] = s;
}

// ---------------- launcher ----------------
extern "C" void kernel_launch(void* const* d_in, const int* in_sizes, int n_in,
                              void* d_out, int out_size, void* d_ws, size_t ws_size,
                              hipStream_t stream) {
  const float* x    = (const float*)d_in[0];
  const float* Win  = (const float*)d_in[1];
  const float* Whg  = (const float*)d_in[2];
  const float* Wout = (const float*)d_in[3];
  const float* Wfin = (const float*)d_in[4];
  float* out = (float*)d_out;
  char* ws = (char*)d_ws;

  u16*   xb    = (u16*)(ws + OFF_XB);
  u16*   B2c   = (u16*)(ws + OFF_B2C);
  float* wc    = (float*)(ws + OFF_WC);
  float* SegC  = (float*)(ws + OFF_SEGC);
  float* SegVH = (float*)(ws + OFF_SEGVH);
  float* part  = (float*)(ws + OFF_PART);

  prep_xb   <<<2048, 256, 0, stream>>>(x, xb);
  prep_b2c  <<<384,  256, 0, stream>>>(Win, Whg, B2c);
  prep_wcomb<<<192,  256, 0, stream>>>(Wout, Wfin, wc);
  fused_gemm_scan<1><<<NCHUNK * DTILES, 256, 0, stream>>>(xb, B2c, SegVH, wc, SegC, SegVH, part);
  scan_carry<<<BB, DI, 0, stream>>>(SegC, SegVH);
  fused_gemm_scan<2><<<NCHUNK * DTILES, 256, 0, stream>>>(xb, B2c, SegVH, wc, SegC, SegVH, part);
  reduce12  <<<256,  256, 0, stream>>>(part, out);
}

// Round 6
// 137.427 us; speedup vs baseline: 1.1031x; 1.1031x over previous
//
#include <hip/hip_runtime.h>
#include <hip/hip_fp16.h>

typedef unsigned short u16;
typedef unsigned int   u32;
typedef __bf16 bf16x8 __attribute__((ext_vector_type(8)));
typedef float  f32x4  __attribute__((ext_vector_type(4)));

// ---------------- problem constants ----------------
constexpr int BB   = 16;            // batch
constexpr int S    = 4096;          // seq len
constexpr int M    = BB * S;        // 65536 rows
constexpr int DIN  = 64;
constexpr int H    = 512;
constexpr int DI   = 768;
constexpr int N2   = 1536;          // 2*DI
constexpr int CL   = 128;           // chunk length
constexpr int NCHUNK = M / CL;      // 512 chunks total
constexpr int SEGB  = S / 32;       // 128 segments per batch
constexpr int DTILES = 12;          // 768 d / 64 d per tile

// ---------------- workspace layout (bytes) — total ~24.3 MB ----------------
constexpr size_t OFF_XB    = 0;                    // u16 [65536][64]  = 8388608
constexpr size_t OFF_B2C   = 8388608;              // u16 [1536][64]   = 196608
constexpr size_t OFF_WC    = 8585216;              // f32 [768] (pad 4096)
constexpr size_t OFF_SEGC  = 8589312;              // f32 [2048][768]  = 6291456
constexpr size_t OFF_SEGVH = 14880768;             // f32 [2048][768]  (V, then Hin in-place)
constexpr size_t OFF_PART  = 21172224;             // f32 [12][65536]  = 3145728

constexpr float L2E = 1.4426950408889634f;

__device__ __forceinline__ u16 f2bf(float f) {
  u32 u = __float_as_uint(f);
  u32 r = (u + 0x7FFFu + ((u >> 16) & 1u)) >> 16;
  return (u16)r;
}

// swizzled cvl slot (u32 [128][64]): kills 4-way conflict on activation stores
__device__ __forceinline__ int cvs(int row, int d) {
  return row * 64 + (d ^ (((row >> 2) & 3) << 4));
}

// activation: (hidden, gate) -> (c, v), all f32
__device__ __forceinline__ void act_cv(float hidden, float gate,
                                       float& cc, float& vv) {
  float eg  = __builtin_amdgcn_exp2f(gate * L2E);
  cc = __builtin_amdgcn_rcpf(1.0f + eg);            // sigmoid(-gate)
  float zz  = eg * cc;                              // sigmoid(gate)
  float gneg = __builtin_amdgcn_rcpf(
                  1.0f + __builtin_amdgcn_exp2f(-hidden * L2E));
  float gg  = (hidden >= 0.0f) ? (hidden + 0.5f) : gneg;
  vv = zz * gg;
}

// ordered pair-combine across lanes (lower-lane run precedes upper-lane run)
__device__ __forceinline__ void comb_step(float& C, float& V, int bit, int ln) {
  float Cp = __shfl_xor(C, bit);
  float Vp = __shfl_xor(V, bit);
  bool up = (ln & bit) != 0;
  V = up ? fmaf(C, Vp, V) : fmaf(Cp, V, Vp);
  C *= Cp;
}

// ---------------- prep: x f32 -> bf16 ----------------
__global__ __launch_bounds__(256) void prep_xb(const float* __restrict__ x,
                                               u16* __restrict__ xb) {
  size_t i = (size_t)(blockIdx.x * 256 + threadIdx.x) * 8;   // 4194304 elems
  float4 f0 = *(const float4*)(x + i);
  float4 f1 = *(const float4*)(x + i + 4);
  u32 w0 = f2bf(f0.x) | ((u32)f2bf(f0.y) << 16);
  u32 w1 = f2bf(f0.z) | ((u32)f2bf(f0.w) << 16);
  u32 w2 = f2bf(f1.x) | ((u32)f2bf(f1.y) << 16);
  u32 w3 = f2bf(f1.z) | ((u32)f2bf(f1.w) << 16);
  uint4 o = make_uint4(w0, w1, w2, w3);
  *(uint4*)(xb + i) = o;
}

// ---------------- prep: B2c[n][k] = bf16( (W_in @ W_hg)[k][pi(n)] ) --------
// pi: n = 32g + r : r<16 -> hidden col (16g+r) ; r>=16 -> gate col (768+16g+(r-16))
__global__ __launch_bounds__(256) void prep_b2c(const float* __restrict__ Win,
                                                const float* __restrict__ Whg,
                                                u16* __restrict__ B2c) {
  __shared__ float Wl[64][65];
  const int tid = threadIdx.x;
  const int k = tid & 63;
  const int nloc = tid >> 6;                  // 0..3
  const int n = blockIdx.x * 4 + nloc;        // 384 blocks -> 1536 n
  const int g = n >> 5, r = n & 31;
  const int col = (r < 16) ? (g * 16 + r) : (DI + g * 16 + (r - 16));
  float acc = 0.f;
  for (int jc = 0; jc < H; jc += 64) {
    const int jl = tid & 63, k0 = tid >> 6;
    #pragma unroll
    for (int s = 0; s < 16; ++s) {
      int kr = k0 + 4 * s;
      Wl[kr][jl] = Win[kr * H + jc + jl];
    }
    __syncthreads();
    #pragma unroll 8
    for (int j = 0; j < 64; ++j)
      acc = fmaf(Wl[k][j], Whg[(size_t)(jc + j) * N2 + col], acc);
    __syncthreads();
  }
  B2c[n * 64 + k] = f2bf(acc);
}

// ---------------- prep: wcomb[d] = W_out[d,:] . W_final ----------------
__global__ __launch_bounds__(256) void prep_wcomb(const float* __restrict__ Wout,
                                                  const float* __restrict__ Wfin,
                                                  float* __restrict__ wc) {
  int wv = threadIdx.x >> 6, ln = threadIdx.x & 63;
  int d = blockIdx.x * 4 + wv;                // 192 blocks -> 768 d
  const float* row = Wout + (size_t)d * H;
  float s = 0.f;
  #pragma unroll
  for (int j = 0; j < 8; ++j) {
    int k = j * 64 + ln;
    s += row[k] * Wfin[k];
  }
  #pragma unroll
  for (int off = 32; off; off >>= 1) s += __shfl_xor(s, off);
  if (ln == 0) wc[d] = s;
}

// -------- fused: GEMM(K=64) + activation + segment scan --------
// PASS 1: per-SEGMENT (32-row) summaries (fragment-direct, in-register)
// PASS 2: read segment carry (SegVH==Hin), apply + fused wcomb dot -> part
template<int PASS>
__global__ __launch_bounds__(256) void fused_gemm_scan(
    const u16* __restrict__ xb, const u16* __restrict__ B2c,
    const float* __restrict__ Hin, const float* __restrict__ wcomb,
    float* __restrict__ SegC, float* __restrict__ SegV,
    float* __restrict__ part) {
  __shared__ __align__(16) u16 AB[16384];     // A [0..8191], B [8192..]; later cvl [128][64] u32
  u32* cvl = (u32*)AB;

  const int tid = threadIdx.x, wv = tid >> 6, ln = tid & 63;
  const int nt = blockIdx.x % DTILES, ck = blockIdx.x / DTILES;
  const int m0 = ck * CL;
  const int wr = wv >> 1, wcol = wv & 1;
  const int lrow = ln & 15, hi4 = ln >> 4;

  // stage A (128x64 bf16) and B (128x64 bf16); XOR-swizzled 16B slots
  {
    const uint4* gA = (const uint4*)(xb + (size_t)m0 * 64);
    const uint4* gB = (const uint4*)(B2c + (size_t)nt * 128 * 64);
    uint4* lA = (uint4*)AB;
    uint4* lB = (uint4*)(AB + 8192);
    #pragma unroll
    for (int j = 0; j < 4; ++j) {
      int q = j * 256 + tid;                  // slot id 0..1023 (8 slots/row)
      int qs = (q & ~7) | ((q & 7) ^ ((q >> 3) & 7));
      lA[qs] = gA[q];
      lB[qs] = gB[q];
    }
  }
  __syncthreads();

  f32x4 acc[4][4] = {};
  {
    const u16* Al = AB;
    const u16* Bl = AB + 8192;
    #pragma unroll
    for (int kk = 0; kk < 2; ++kk) {
      bf16x8 af[4], bfr[4];
      #pragma unroll
      for (int i = 0; i < 4; ++i) {
        int row = wr * 64 + i * 16 + lrow;
        af[i] = *(const bf16x8*)&Al[row * 64 + (((kk * 4 + hi4) ^ (row & 7)) << 3)];
      }
      #pragma unroll
      for (int j = 0; j < 4; ++j) {
        int row = wcol * 64 + j * 16 + lrow;
        bfr[j] = *(const bf16x8*)&Bl[row * 64 + (((kk * 4 + hi4) ^ (row & 7)) << 3)];
      }
      #pragma unroll
      for (int i = 0; i < 4; ++i)
        #pragma unroll
        for (int j = 0; j < 4; ++j)
          acc[i][j] = __builtin_amdgcn_mfma_f32_16x16x32_bf16(af[i], bfr[j], acc[i][j], 0, 0, 0);
    }
  }

  if (PASS == 1) {
    // fragment-direct segment summaries; no LDS, no fp16.
    // thread rows: wr*64 + i*16 + hi4*4 + r ; segment sl: rows [sl*32, sl*32+32)
    #pragma unroll
    for (int jp = 0; jp < 2; ++jp) {
      const int d = nt * 64 + (wcol * 2 + jp) * 16 + lrow;
      #pragma unroll
      for (int sl = 0; sl < 2; ++sl) {
        float Cr[2], Vr[2];
        #pragma unroll
        for (int ii = 0; ii < 2; ++ii) {
          const int i = sl * 2 + ii;
          float C = 1.f, V = 0.f;
          #pragma unroll
          for (int r = 0; r < 4; ++r) {
            float cc, vvv;
            act_cv(acc[i][2 * jp + 0][r], acc[i][2 * jp + 1][r], cc, vvv);
            V = fmaf(cc, V, vvv);
            C *= cc;
          }
          comb_step(C, V, 16, ln);    // hi4 pairs (rows +0..3 | +4..7)
          comb_step(C, V, 32, ln);    // quads     (rows +0..7 | +8..15)
          Cr[ii] = C; Vr[ii] = V;
        }
        float Cs = Cr[0] * Cr[1];
        float Vs = fmaf(Cr[1], Vr[0], Vr[1]);
        if (hi4 == 0) {
          int seg = ck * 4 + wr * 2 + sl;
          SegC[(size_t)seg * DI + d] = Cs;
          SegV[(size_t)seg * DI + d] = Vs;
        }
      }
    }
  } else {
    __syncthreads();   // LDS fragment reads done -> safe to overwrite as cvl

    // activation -> packed fp16 (c,v) in LDS
    #pragma unroll
    for (int i = 0; i < 4; ++i)
      #pragma unroll
      for (int jp = 0; jp < 2; ++jp) {
        const int dl = (wcol * 2 + jp) * 16 + lrow;   // 0..63
        #pragma unroll
        for (int r = 0; r < 4; ++r) {
          int row = wr * 64 + i * 16 + hi4 * 4 + r;   // 0..127
          float cc, vvv;
          act_cv(acc[i][2 * jp + 0][r], acc[i][2 * jp + 1][r], cc, vvv);
          __half2 p = __floats2half2_rn(cc, vvv);
          cvl[cvs(row, dl)] = *(const u32*)&p;
        }
      }
    __syncthreads();

    // carried apply + in-place rotated pv store (wave owns its 32 rows)
    const int seg = ck * 4 + wv;
    float h = Hin[(size_t)seg * DI + nt * 64 + ln];
    const float wd = wcomb[nt * 64 + ln];
    #pragma unroll 4
    for (int tt = 0; tt < 32; ++tt) {
      const int t = wv * 32 + tt;
      u32 u = cvl[cvs(t, ln)];
      float hn;
      // h = f16lo(u) * h + f16hi(u)   (one VOP3P mix fma)
      asm("v_fma_mix_f32 %0, %1, %2, %1 op_sel:[0,0,1] op_sel_hi:[1,0,1]"
          : "=v"(hn) : "v"(u), "v"(h));
      h = hn;
      float pv = h * wd;
      cvl[t * 64 + ((ln + t) & 63)] = __float_as_uint(pv);
    }
    __syncthreads();
    // row reduction: 2 threads per row, rotated (conflict-free) reads
    const int row = tid >> 1, half = tid & 1;
    float s = 0.f;
    #pragma unroll 8
    for (int jj = 0; jj < 32; ++jj) {
      int idx = (half * 32 + jj + row) & 63;
      s += __uint_as_float(cvl[row * 64 + idx]);
    }
    s += __shfl_xor(s, 1);
    if (half == 0) part[(size_t)nt * M + m0 + row] = s;
  }
}

// ------- cross-segment carry scan; converts SegVH: V -> Hin in place -------
// 96 blocks x 128 threads; loads batched 16-deep to hide latency
__global__ __launch_bounds__(128) void scan_carry(const float* __restrict__ SegC,
                                                  float* __restrict__ SegVH) {
  const int b = blockIdx.x / 6, dc = blockIdx.x % 6;
  const int d = dc * 128 + threadIdx.x;
  const size_t base = (size_t)b * SEGB * DI + d;
  float carry = 0.f;
  for (int q0 = 0; q0 < SEGB; q0 += 16) {
    float c16[16], v16[16];
    #pragma unroll
    for (int j = 0; j < 16; ++j) {
      size_t idx = base + (size_t)(q0 + j) * DI;
      c16[j] = SegC[idx];
      v16[j] = SegVH[idx];
    }
    #pragma unroll
    for (int j = 0; j < 16; ++j) {
      size_t idx = base + (size_t)(q0 + j) * DI;
      SegVH[idx] = carry;
      carry = fmaf(c16[j], carry, v16[j]);
    }
  }
}

// ---------------- final: sum 12 d-tile partials ----------------
__global__ __launch_bounds__(256) void reduce12(const float* __restrict__ part,
                                                float* __restrict__ out) {
  int i = blockIdx.x * 256 + threadIdx.x;     // 65536
  float s = 0.f;
  #pragma unroll
  for (int w = 0; w < DTILES; ++w) s += part[(size_t)w * M + i];
  out[i] = s;
}

// ---------------- launcher ----------------
extern "C" void kernel_launch(void* const* d_in, const int* in_sizes, int n_in,
                              void* d_out, int out_size, void* d_ws, size_t ws_size,
                              hipStream_t stream) {
  const float* x    = (const float*)d_in[0];
  const float* Win  = (const float*)d_in[1];
  const float* Whg  = (const float*)d_in[2];
  const float* Wout = (const float*)d_in[3];
  const float* Wfin = (const float*)d_in[4];
  float* out = (float*)d_out;
  char* ws = (char*)d_ws;

  u16*   xb    = (u16*)(ws + OFF_XB);
  u16*   B2c   = (u16*)(ws + OFF_B2C);
  float* wc    = (float*)(ws + OFF_WC);
  float* SegC  = (float*)(ws + OFF_SEGC);
  float* SegVH = (float*)(ws + OFF_SEGVH);
  float* part  = (float*)(ws + OFF_PART);

  prep_xb   <<<2048, 256, 0, stream>>>(x, xb);
  prep_b2c  <<<384,  256, 0, stream>>>(Win, Whg, B2c);
  prep_wcomb<<<192,  256, 0, stream>>>(Wout, Wfin, wc);
  fused_gemm_scan<1><<<NCHUNK * DTILES, 256, 0, stream>>>(xb, B2c, SegVH, wc, SegC, SegVH, part);
  scan_carry<<<96, 128, 0, stream>>>(SegC, SegVH);
  fused_gemm_scan<2><<<NCHUNK * DTILES, 256, 0, stream>>>(xb, B2c, SegVH, wc, SegC, SegVH, part);
  reduce12  <<<256,  256, 0, stream>>>(part, out);
}